// Round 1
// baseline (279.305 us; speedup 1.0000x reference)
//
#include <hip/hip_runtime.h>
#include <hip/hip_bf16.h>

// ---------------------------------------------------------------------------
// QuantumImageEncoder: conv->pool->conv->pool->fc1->fc2->BN->4-wire quantum sim
// Pipeline: prep (build 16x16 unitary + zero stats) -> transpose fc1_w ->
//           conv backbone -> fc(+BN stats) -> quantum measure
// ---------------------------------------------------------------------------

#define B_EPS 1e-5f

// ---------------- prep: build U = G30*...*G1 (16x16 complex), zero stats ----
__global__ void prep_kernel(const float* __restrict__ rl,
                            float* __restrict__ Uout,
                            float* __restrict__ stats)
{
    __shared__ float2 U[16][16];
    int t = threadIdx.x;                 // 256 threads
    int r = t >> 4, cc = t & 15;
    U[r][cc] = (r == cc) ? make_float2(1.f, 0.f) : make_float2(0.f, 0.f);
    if (t < 8) stats[t] = 0.f;
    __syncthreads();
    for (int op = 0; op < 30; op++) {
        int kind = op & 3;               // 0=rx,1=ry,2=rz,3=cnot ; wire = op%4
        float2 cur = U[r][cc];
        float2 nv;
        if (kind == 3) {
            // cnot: control wire3 (bit mask 1), target wire0 (bit mask 8)
            float2 part = U[r ^ 8][cc];
            nv = (r & 1) ? part : cur;
        } else {
            int m = 8 >> kind;           // wire w=kind -> bit (3-w)
            float theta = rl[op - (op >> 2)];
            float ch = cosf(0.5f * theta), sh = sinf(0.5f * theta);
            float2 part = U[r ^ m][cc];
            int br = (r & m) ? 1 : 0;
            float2 gc, gp;
            if (kind == 0)      { gc = make_float2(ch, 0.f);              gp = make_float2(0.f, -sh); }
            else if (kind == 1) { gc = make_float2(ch, 0.f);              gp = make_float2(br ? sh : -sh, 0.f); }
            else                { gc = make_float2(ch, br ? sh : -sh);    gp = make_float2(0.f, 0.f); }
            nv.x = gc.x*cur.x - gc.y*cur.y + gp.x*part.x - gp.y*part.y;
            nv.y = gc.x*cur.y + gc.y*cur.x + gp.x*part.y + gp.y*part.x;
        }
        __syncthreads();
        U[r][cc] = nv;
        __syncthreads();
    }
    ((float2*)Uout)[t] = U[r][cc];
}

// ---------------- transpose fc1_w [64,784] -> wT [784,64] -------------------
__global__ void tr_kernel(const float* __restrict__ w, float* __restrict__ wT)
{
    int id = blockIdx.x * 256 + threadIdx.x;
    if (id < 784 * 64) {
        int k = id >> 6, o = id & 63;
        wT[id] = w[o * 784 + k];
    }
}

// ---------------- conv backbone: 2 samples / block --------------------------
__global__ __launch_bounds__(256) void conv_kernel(
    const float* __restrict__ x,  const float* __restrict__ c1w,
    const float* __restrict__ c1b, const float* __restrict__ c2w,
    const float* __restrict__ c2b, float* __restrict__ flat)
{
    __shared__ float xin[2][30][36];      // padded 28x28 (+1 halo), stride 36 breaks bank aliasing
    __shared__ float p1 [2][8][16][20];   // padded 14x14 (+1 halo), stride 20
    __shared__ float p2 [2][16 * 49];
    __shared__ float w1s[72], b1s[8], w2s[16 * 72], b2s[16];

    int t = threadIdx.x;
    for (int i = t; i < 2*30*36;    i += 256) ((float*)xin)[i] = 0.f;
    for (int i = t; i < 2*8*16*20;  i += 256) ((float*)p1)[i]  = 0.f;
    if (t < 72) w1s[t] = c1w[t];
    if (t < 8)  b1s[t] = c1b[t];
    for (int i = t; i < 16*72; i += 256) w2s[i] = c2w[i];
    if (t < 16) b2s[t] = c2b[t];
    __syncthreads();

    const float* xg = x + (size_t)blockIdx.x * 2 * 784;
    for (int i = t; i < 2*784; i += 256) {
        int s = i / 784; int rem = i - s * 784;
        int rr = rem / 28, ccol = rem - rr * 28;
        xin[s][rr + 1][ccol + 1] = xg[i];
    }
    __syncthreads();

    // ---- conv1 + relu + pool : thread = (sample, out_ch(8), pooled_row(14))
    if (t < 224) {
        int s = t / 112, rr = t % 112;
        int c = rr / 14, i = rr % 14;
        float w[9];
        #pragma unroll
        for (int q = 0; q < 9; q++) w[q] = w1s[c * 9 + q];
        float bias = b1s[c];
        #pragma unroll
        for (int half = 0; half < 2; half++) {
            int cb = half * 14;
            float r0[16], r1[16], r2[16], r3[16];
            #pragma unroll
            for (int q = 0; q < 16; q++) {
                r0[q] = xin[s][2*i + 0][cb + q];
                r1[q] = xin[s][2*i + 1][cb + q];
                r2[q] = xin[s][2*i + 2][cb + q];
                r3[q] = xin[s][2*i + 3][cb + q];
            }
            #pragma unroll
            for (int jj = 0; jj < 7; jj++) {
                int q = 2 * jj;
                float vA = bias, vB = bias, vC = bias, vD = bias;
                #pragma unroll
                for (int kx = 0; kx < 3; kx++) {
                    vA += w[kx]*r0[q+kx]   + w[3+kx]*r1[q+kx]   + w[6+kx]*r2[q+kx];
                    vB += w[kx]*r0[q+1+kx] + w[3+kx]*r1[q+1+kx] + w[6+kx]*r2[q+1+kx];
                    vC += w[kx]*r1[q+kx]   + w[3+kx]*r2[q+kx]   + w[6+kx]*r3[q+kx];
                    vD += w[kx]*r1[q+1+kx] + w[3+kx]*r2[q+1+kx] + w[6+kx]*r3[q+1+kx];
                }
                float m = fmaxf(fmaxf(vA, vB), fmaxf(vC, vD));
                p1[s][c][i + 1][1 + half*7 + jj] = fmaxf(m, 0.f);
            }
        }
    }
    __syncthreads();

    // ---- conv2 + relu + pool : thread = (sample, out_ch(16), pooled_row(7))
    if (t < 224) {
        int s = t / 112, rr = t % 112;
        int c = rr / 7, i = rr % 7;
        float acc0[14], acc1[14];
        float bias = b2s[c];
        #pragma unroll
        for (int q = 0; q < 14; q++) { acc0[q] = bias; acc1[q] = bias; }
        for (int ci = 0; ci < 8; ci++) {
            float w[9];
            #pragma unroll
            for (int q = 0; q < 9; q++) w[q] = w2s[c*72 + ci*9 + q];
            float r0[16], r1[16], r2[16], r3[16];
            #pragma unroll
            for (int q = 0; q < 16; q++) {
                r0[q] = p1[s][ci][2*i + 0][q];
                r1[q] = p1[s][ci][2*i + 1][q];
                r2[q] = p1[s][ci][2*i + 2][q];
                r3[q] = p1[s][ci][2*i + 3][q];
            }
            #pragma unroll
            for (int q = 0; q < 14; q++) {
                #pragma unroll
                for (int kx = 0; kx < 3; kx++) {
                    acc0[q] += w[kx]*r0[q+kx] + w[3+kx]*r1[q+kx] + w[6+kx]*r2[q+kx];
                    acc1[q] += w[kx]*r1[q+kx] + w[3+kx]*r2[q+kx] + w[6+kx]*r3[q+kx];
                }
            }
        }
        #pragma unroll
        for (int j = 0; j < 7; j++) {
            float m = fmaxf(fmaxf(acc0[2*j], acc0[2*j+1]), fmaxf(acc1[2*j], acc1[2*j+1]));
            p2[s][c*49 + i*7 + j] = fmaxf(m, 0.f);
        }
    }
    __syncthreads();

    float* fg = flat + (size_t)blockIdx.x * 2 * 784;
    for (int i = t; i < 2*784; i += 256) {
        int s = i / 784; int rem = i - s * 784;
        fg[i] = p2[s][rem];
    }
}

// ---------------- fc1 + relu + fc2 + BN partial stats -----------------------
// 16 samples / block; 4 waves split K=784; lane = output neuron (64)
__global__ __launch_bounds__(256) void fc_kernel(
    const float* __restrict__ flat, const float* __restrict__ wT,
    const float* __restrict__ fc1_b, const float* __restrict__ fc2_w,
    const float* __restrict__ fc2_b, float* __restrict__ feat,
    float* __restrict__ stats)
{
    __shared__ float part[4][16][64];
    __shared__ float hbuf[16][65];
    int t = threadIdx.x;
    int lane = t & 63;
    int wv = t >> 6;
    const float* fl = flat + (size_t)blockIdx.x * 16 * 784;
    float acc[16];
    #pragma unroll
    for (int i = 0; i < 16; i++) acc[i] = 0.f;
    int kbase = wv * 196;
    for (int kk = 0; kk < 196; kk += 4) {
        int k = kbase + kk;
        float w0 = wT[(k + 0) * 64 + lane];
        float w1 = wT[(k + 1) * 64 + lane];
        float w2 = wT[(k + 2) * 64 + lane];
        float w3 = wT[(k + 3) * 64 + lane];
        #pragma unroll
        for (int i = 0; i < 16; i++) {
            float4 f = *(const float4*)(fl + i * 784 + k);
            acc[i] = fmaf(f.x, w0, fmaf(f.y, w1, fmaf(f.z, w2, fmaf(f.w, w3, acc[i]))));
        }
    }
    #pragma unroll
    for (int i = 0; i < 16; i++) part[wv][i][lane] = acc[i];
    __syncthreads();
    for (int e = t; e < 16 * 64; e += 256) {
        int i = e >> 6, o = e & 63;
        float h = part[0][i][o] + part[1][i][o] + part[2][i][o] + part[3][i][o] + fc1_b[o];
        hbuf[i][o] = fmaxf(h, 0.f);
    }
    __syncthreads();
    if (t < 64) {
        int ls = t >> 2, j = t & 3;
        float a = fc2_b[j];
        #pragma unroll
        for (int o = 0; o < 64; o++) a += hbuf[ls][o] * fc2_w[j * 64 + o];
        feat[(size_t)(blockIdx.x * 16 + ls) * 4 + j] = a;
        float s1 = a, s2 = a * a;
        #pragma unroll
        for (int off = 4; off < 64; off <<= 1) {
            s1 += __shfl_xor(s1, off, 64);
            s2 += __shfl_xor(s2, off, 64);
        }
        if (lane < 4) {
            atomicAdd(&stats[j], s1);
            atomicAdd(&stats[4 + j], s2);
        }
    }
}

// ---------------- BN + encoder + U matvec + PauliZ measure ------------------
__global__ __launch_bounds__(128) void quantum_kernel(
    const float* __restrict__ feat, const float* __restrict__ Ug,
    const float* __restrict__ stats, const float* __restrict__ bn_g,
    const float* __restrict__ bn_b, float* __restrict__ out, int B)
{
    __shared__ float2 Us[256];
    int t = threadIdx.x;
    for (int i = t; i < 256; i += 128) Us[i] = ((const float2*)Ug)[i];
    __syncthreads();
    int s = blockIdx.x * 128 + t;
    float4 fv = ((const float4*)feat)[s];
    float f[4] = {fv.x, fv.y, fv.z, fv.w};
    float cn[4], sn[4];
    float invB = 1.0f / (float)B;
    #pragma unroll
    for (int w = 0; w < 4; w++) {
        float mean = stats[w] * invB;
        float var  = stats[4 + w] * invB - mean * mean;
        float fh = (f[w] - mean) / sqrtf(var + B_EPS) * bn_g[w] + bn_b[w];
        cn[w] = cosf(0.5f * fh);
        sn[w] = sinf(0.5f * fh);
    }
    // encoded product state: s0_k = prod(c/s) * (-i)^popcount(k)
    float re0[16], im0[16];
    #pragma unroll
    for (int k = 0; k < 16; k++) {
        float mag = ((k & 8) ? sn[0] : cn[0]) * ((k & 4) ? sn[1] : cn[1]) *
                    ((k & 2) ? sn[2] : cn[2]) * ((k & 1) ? sn[3] : cn[3]);
        int m = __popc(k) & 3;
        re0[k] = (m == 0) ? mag : (m == 2) ? -mag : 0.f;
        im0[k] = (m == 1) ? -mag : (m == 3) ? mag : 0.f;
    }
    float o0 = 0.f, o1 = 0.f, o2 = 0.f, o3 = 0.f;
    #pragma unroll
    for (int r = 0; r < 16; r++) {
        float ar = 0.f, ai = 0.f;
        #pragma unroll
        for (int k = 0; k < 16; k++) {
            float2 u = Us[r * 16 + k];
            ar += u.x * re0[k] - u.y * im0[k];
            ai += u.x * im0[k] + u.y * re0[k];
        }
        float p = ar * ar + ai * ai;
        o0 += (r & 8) ? -p : p;
        o1 += (r & 4) ? -p : p;
        o2 += (r & 2) ? -p : p;
        o3 += (r & 1) ? -p : p;
    }
    float4 ov = {o0, o1, o2, o3};
    ((float4*)out)[s] = ov;
}

// ---------------------------------------------------------------------------
extern "C" void kernel_launch(void* const* d_in, const int* in_sizes, int n_in,
                              void* d_out, int out_size, void* d_ws, size_t ws_size,
                              hipStream_t stream)
{
    const float* x   = (const float*)d_in[0];
    const float* c1w = (const float*)d_in[1];
    const float* c1b = (const float*)d_in[2];
    const float* c2w = (const float*)d_in[3];
    const float* c2b = (const float*)d_in[4];
    const float* f1w = (const float*)d_in[5];
    const float* f1b = (const float*)d_in[6];
    const float* f2w = (const float*)d_in[7];
    const float* f2b = (const float*)d_in[8];
    const float* bng = (const float*)d_in[9];
    const float* bnb = (const float*)d_in[10];
    const float* rl  = (const float*)d_in[11];
    float* out = (float*)d_out;

    int B = in_sizes[0] / 784;

    float* wsf   = (float*)d_ws;
    float* flat  = wsf;                          // B*784
    float* feat  = flat + (size_t)B * 784;       // B*4
    float* wT    = feat + (size_t)B * 4;         // 784*64
    float* U     = wT + 784 * 64;                // 512 (float2[256])
    float* stats = U + 512;                      // 8

    prep_kernel<<<1, 256, 0, stream>>>(rl, U, stats);
    tr_kernel<<<(784 * 64 + 255) / 256, 256, 0, stream>>>(f1w, wT);
    conv_kernel<<<B / 2, 256, 0, stream>>>(x, c1w, c1b, c2w, c2b, flat);
    fc_kernel<<<B / 16, 256, 0, stream>>>(flat, wT, f1b, f2w, f2b, feat, stats);
    quantum_kernel<<<B / 128, 128, 0, stream>>>(feat, U, stats, bng, bnb, out, B);
}

// Round 2
// 240.367 us; speedup vs baseline: 1.1620x; 1.1620x over previous
//
#include <hip/hip_runtime.h>
#include <hip/hip_bf16.h>

// ---------------------------------------------------------------------------
// QuantumImageEncoder: conv->pool->conv->pool->fc1->fc2->BN->4-wire quantum sim
// R2: conflict-free broadcast LDS layout for conv; (channel,colgroup) lane map;
//     b64 vector LDS reads; prep+transpose merged.
// ---------------------------------------------------------------------------

#define B_EPS 1e-5f

// p1 (pooled conv1 output) LDS layout: [sample][ch][row 16][col 18], padded
#define P1_RS 18          // row stride (floats); cols 0..17, 16/17 always zero
#define P1_CS 292         // channel stride = 16*18 + 4  (=> 4*c mod 32: conflict-free writes)
#define P1_FLOATS (8 * P1_CS)   // per sample

// ---------------- prep: build U (block 0) + transpose fc1_w (blocks 1..196) -
__global__ void prep_kernel(const float* __restrict__ rl,
                            const float* __restrict__ f1w,
                            float* __restrict__ Uout,
                            float* __restrict__ wT,
                            float* __restrict__ stats)
{
    if (blockIdx.x == 0) {
        __shared__ float2 U[16][16];
        int t = threadIdx.x;                 // 256 threads
        int r = t >> 4, cc = t & 15;
        U[r][cc] = (r == cc) ? make_float2(1.f, 0.f) : make_float2(0.f, 0.f);
        if (t < 8) stats[t] = 0.f;
        __syncthreads();
        for (int op = 0; op < 30; op++) {
            int kind = op & 3;               // 0=rx,1=ry,2=rz,3=cnot ; wire = op%4
            float2 cur = U[r][cc];
            float2 nv;
            if (kind == 3) {
                float2 part = U[r ^ 8][cc];  // control wire3 (bit 1), target wire0 (bit 8)
                nv = (r & 1) ? part : cur;
            } else {
                int m = 8 >> kind;           // wire w=kind -> bit (3-w)
                float theta = rl[op - (op >> 2)];
                float ch = cosf(0.5f * theta), sh = sinf(0.5f * theta);
                float2 part = U[r ^ m][cc];
                int br = (r & m) ? 1 : 0;
                float2 gc, gp;
                if (kind == 0)      { gc = make_float2(ch, 0.f);           gp = make_float2(0.f, -sh); }
                else if (kind == 1) { gc = make_float2(ch, 0.f);           gp = make_float2(br ? sh : -sh, 0.f); }
                else                { gc = make_float2(ch, br ? sh : -sh); gp = make_float2(0.f, 0.f); }
                nv.x = gc.x*cur.x - gc.y*cur.y + gp.x*part.x - gp.y*part.y;
                nv.y = gc.x*cur.y + gc.y*cur.x + gp.x*part.y + gp.y*part.x;
            }
            __syncthreads();
            U[r][cc] = nv;
            __syncthreads();
        }
        ((float2*)Uout)[t] = U[r][cc];
    } else {
        int id = (blockIdx.x - 1) * 256 + threadIdx.x;
        if (id < 784 * 64) {
            int k = id >> 6, o = id & 63;
            wT[id] = f1w[o * 784 + k];
        }
    }
}

// ---------------- conv backbone: 2 samples / block, 4 waves -----------------
// wave w: sample s=w>>1, half h=w&1.
// conv1 lane map: c = lane>>3 (8 ch), g = lane&7 (col group of 4; g<7 active)
// conv2 lane map: c2 = lane>>2 (16 ch), g2 = lane&3 (col group of 4)
// Broadcast pattern: lanes sharing a col-group read identical LDS addresses
// (free broadcast); distinct groups hit distinct banks -> conflict-free.
__global__ __launch_bounds__(256) void conv_kernel(
    const float* __restrict__ x,  const float* __restrict__ c1w,
    const float* __restrict__ c1b, const float* __restrict__ c2w,
    const float* __restrict__ c2b, float* __restrict__ flat)
{
    __shared__ union alignas(16) {
        float xin[2][30 * 32];     // padded 28x28, row stride 32, halo ring
        float flat[2][784];        // reused after conv1
    } u;
    __shared__ alignas(16) float p1[2][P1_FLOATS];
    __shared__ float w1s[8][9], b1s[8], w2s[16][73], b2s[16];

    int t = threadIdx.x;
    int w = t >> 6, lane = t & 63;

    // ---- zero xin + p1 (halo correctness), load weights
    {
        float4 z = make_float4(0.f, 0.f, 0.f, 0.f);
        float4* xz = (float4*)u.xin;
        for (int i = t; i < 2 * 30 * 32 / 4; i += 256) xz[i] = z;
        float4* pz = (float4*)p1;
        for (int i = t; i < 2 * P1_FLOATS / 4; i += 256) pz[i] = z;
    }
    if (t < 72) ((float*)w1s)[t] = c1w[t];
    if (t < 8)  b1s[t] = c1b[t];
    for (int i = t; i < 16 * 72; i += 256) w2s[i / 72][i % 72] = c2w[i];
    if (t < 16) b2s[t] = c2b[t];
    __syncthreads();

    // ---- stage input (2 samples), shifted +1 for the zero halo
    {
        const float4* xg = (const float4*)(x + (size_t)blockIdx.x * 2 * 784);
        for (int i = t; i < 392; i += 256) {
            float4 v = xg[i];
            int s = i / 196, q = (i - s * 196) * 4;
            float vv[4] = {v.x, v.y, v.z, v.w};
            #pragma unroll
            for (int j = 0; j < 4; j++) {
                int p = q + j, rr = p / 28, cc = p - rr * 28;
                u.xin[s][(rr + 1) * 32 + cc + 1] = vv[j];
            }
        }
    }
    __syncthreads();

    // ---- conv1 + relu + pool -> p1
    {
        int s = w >> 1, h = w & 1;
        int c = lane >> 3, g = lane & 7;
        if (g < 7) {
            float wk[9];
            #pragma unroll
            for (int q = 0; q < 9; q++) wk[q] = w1s[c][q];
            float bias = b1s[c];
            const float* xb = &u.xin[s][4 * g];
            float* pout = &p1[s][c * P1_CS];
            for (int ii = 0; ii < 7; ii++) {
                int i = h * 7 + ii;                     // pooled row 0..13
                const float* r = xb + 2 * i * 32;
                float rv[4][6];
                #pragma unroll
                for (int dr = 0; dr < 4; dr++) {
                    float2 a = *(const float2*)(r + dr * 32);
                    float2 b = *(const float2*)(r + dr * 32 + 2);
                    float2 c2v = *(const float2*)(r + dr * 32 + 4);
                    rv[dr][0] = a.x;  rv[dr][1] = a.y;
                    rv[dr][2] = b.x;  rv[dr][3] = b.y;
                    rv[dr][4] = c2v.x; rv[dr][5] = c2v.y;
                }
                float o[2][4];
                #pragma unroll
                for (int dr = 0; dr < 2; dr++)
                    #pragma unroll
                    for (int j = 0; j < 4; j++) {
                        float acc = bias;
                        #pragma unroll
                        for (int ky = 0; ky < 3; ky++)
                            #pragma unroll
                            for (int kx = 0; kx < 3; kx++)
                                acc = fmaf(wk[ky * 3 + kx], rv[dr + ky][j + kx], acc);
                        o[dr][j] = acc;
                    }
                #pragma unroll
                for (int jj = 0; jj < 2; jj++) {
                    float m = fmaxf(fmaxf(o[0][2 * jj], o[0][2 * jj + 1]),
                                    fmaxf(o[1][2 * jj], o[1][2 * jj + 1]));
                    pout[(i + 1) * P1_RS + 1 + 2 * g + jj] = fmaxf(m, 0.f);
                }
            }
        }
    }
    __syncthreads();

    // ---- conv2 + relu + pool -> u.flat (xin dead now)
    {
        int s = w >> 1, h = w & 1;
        int c2 = lane >> 2, g2 = lane & 3;
        int i0 = h * 4;                                 // h=0: i 0..3, h=1: i 4..6
        float bias = b2s[c2];
        float acc[4][2][4];
        #pragma unroll
        for (int ii = 0; ii < 4; ii++)
            #pragma unroll
            for (int dr = 0; dr < 2; dr++)
                #pragma unroll
                for (int j = 0; j < 4; j++) acc[ii][dr][j] = bias;

        const float* pbase = &p1[s][4 * g2] + i0 * 2 * P1_RS;
        for (int ci = 0; ci < 8; ci++) {
            float wk[9];
            #pragma unroll
            for (int q = 0; q < 9; q++) wk[q] = w2s[c2][ci * 9 + q];
            const float* pc_ = pbase + ci * P1_CS;
            #pragma unroll
            for (int ii = 0; ii < 4; ii++) {
                if (ii < 3 || h == 0) {
                    float rv[4][6];
                    #pragma unroll
                    for (int dr = 0; dr < 4; dr++) {
                        const float* rp = pc_ + (ii * 2 + dr) * P1_RS;
                        float2 a = *(const float2*)rp;
                        float2 b = *(const float2*)(rp + 2);
                        float2 cc = *(const float2*)(rp + 4);
                        rv[dr][0] = a.x;  rv[dr][1] = a.y;
                        rv[dr][2] = b.x;  rv[dr][3] = b.y;
                        rv[dr][4] = cc.x; rv[dr][5] = cc.y;
                    }
                    #pragma unroll
                    for (int dr = 0; dr < 2; dr++)
                        #pragma unroll
                        for (int j = 0; j < 4; j++) {
                            float a2 = acc[ii][dr][j];
                            #pragma unroll
                            for (int ky = 0; ky < 3; ky++)
                                #pragma unroll
                                for (int kx = 0; kx < 3; kx++)
                                    a2 = fmaf(wk[ky * 3 + kx], rv[dr + ky][j + kx], a2);
                            acc[ii][dr][j] = a2;
                        }
                }
            }
        }
        #pragma unroll
        for (int ii = 0; ii < 4; ii++) {
            if (ii < 3 || h == 0) {
                int i = i0 + ii;
                #pragma unroll
                for (int jj = 0; jj < 2; jj++) {
                    int pc = 2 * g2 + jj;
                    if (pc < 7) {
                        float m = fmaxf(fmaxf(acc[ii][0][2 * jj], acc[ii][0][2 * jj + 1]),
                                        fmaxf(acc[ii][1][2 * jj], acc[ii][1][2 * jj + 1]));
                        u.flat[s][c2 * 49 + i * 7 + pc] = fmaxf(m, 0.f);
                    }
                }
            }
        }
    }
    __syncthreads();

    // ---- flush flat to global (coalesced float4)
    {
        float4* fg = (float4*)(flat + (size_t)blockIdx.x * 2 * 784);
        const float4* fs = (const float4*)u.flat;
        for (int i = t; i < 392; i += 256) fg[i] = fs[i];
    }
}

// ---------------- fc1 + relu + fc2 + BN partial stats -----------------------
// 16 samples / block; 4 waves split K=784; lane = output neuron (64)
__global__ __launch_bounds__(256) void fc_kernel(
    const float* __restrict__ flat, const float* __restrict__ wT,
    const float* __restrict__ fc1_b, const float* __restrict__ fc2_w,
    const float* __restrict__ fc2_b, float* __restrict__ feat,
    float* __restrict__ stats)
{
    __shared__ float part[4][16][64];
    __shared__ float hbuf[16][65];
    int t = threadIdx.x;
    int lane = t & 63;
    int wv = t >> 6;
    const float* fl = flat + (size_t)blockIdx.x * 16 * 784;
    float acc[16];
    #pragma unroll
    for (int i = 0; i < 16; i++) acc[i] = 0.f;
    int kbase = wv * 196;
    for (int kk = 0; kk < 196; kk += 4) {
        int k = kbase + kk;
        float w0 = wT[(k + 0) * 64 + lane];
        float w1 = wT[(k + 1) * 64 + lane];
        float w2 = wT[(k + 2) * 64 + lane];
        float w3 = wT[(k + 3) * 64 + lane];
        #pragma unroll
        for (int i = 0; i < 16; i++) {
            float4 f = *(const float4*)(fl + i * 784 + k);
            acc[i] = fmaf(f.x, w0, fmaf(f.y, w1, fmaf(f.z, w2, fmaf(f.w, w3, acc[i]))));
        }
    }
    #pragma unroll
    for (int i = 0; i < 16; i++) part[wv][i][lane] = acc[i];
    __syncthreads();
    for (int e = t; e < 16 * 64; e += 256) {
        int i = e >> 6, o = e & 63;
        float h = part[0][i][o] + part[1][i][o] + part[2][i][o] + part[3][i][o] + fc1_b[o];
        hbuf[i][o] = fmaxf(h, 0.f);
    }
    __syncthreads();
    if (t < 64) {
        int ls = t >> 2, j = t & 3;
        float a = fc2_b[j];
        #pragma unroll
        for (int o = 0; o < 64; o++) a += hbuf[ls][o] * fc2_w[j * 64 + o];
        feat[(size_t)(blockIdx.x * 16 + ls) * 4 + j] = a;
        float s1 = a, s2 = a * a;
        #pragma unroll
        for (int off = 4; off < 64; off <<= 1) {
            s1 += __shfl_xor(s1, off, 64);
            s2 += __shfl_xor(s2, off, 64);
        }
        if (lane < 4) {
            atomicAdd(&stats[j], s1);
            atomicAdd(&stats[4 + j], s2);
        }
    }
}

// ---------------- BN + encoder + U matvec + PauliZ measure ------------------
__global__ __launch_bounds__(128) void quantum_kernel(
    const float* __restrict__ feat, const float* __restrict__ Ug,
    const float* __restrict__ stats, const float* __restrict__ bn_g,
    const float* __restrict__ bn_b, float* __restrict__ out, int B)
{
    __shared__ float2 Us[256];
    int t = threadIdx.x;
    for (int i = t; i < 256; i += 128) Us[i] = ((const float2*)Ug)[i];
    __syncthreads();
    int s = blockIdx.x * 128 + t;
    float4 fv = ((const float4*)feat)[s];
    float f[4] = {fv.x, fv.y, fv.z, fv.w};
    float cn[4], sn[4];
    float invB = 1.0f / (float)B;
    #pragma unroll
    for (int w = 0; w < 4; w++) {
        float mean = stats[w] * invB;
        float var  = stats[4 + w] * invB - mean * mean;
        float fh = (f[w] - mean) / sqrtf(var + B_EPS) * bn_g[w] + bn_b[w];
        cn[w] = cosf(0.5f * fh);
        sn[w] = sinf(0.5f * fh);
    }
    float re0[16], im0[16];
    #pragma unroll
    for (int k = 0; k < 16; k++) {
        float mag = ((k & 8) ? sn[0] : cn[0]) * ((k & 4) ? sn[1] : cn[1]) *
                    ((k & 2) ? sn[2] : cn[2]) * ((k & 1) ? sn[3] : cn[3]);
        int m = __popc(k) & 3;
        re0[k] = (m == 0) ? mag : (m == 2) ? -mag : 0.f;
        im0[k] = (m == 1) ? -mag : (m == 3) ? mag : 0.f;
    }
    float o0 = 0.f, o1 = 0.f, o2 = 0.f, o3 = 0.f;
    #pragma unroll
    for (int r = 0; r < 16; r++) {
        float ar = 0.f, ai = 0.f;
        #pragma unroll
        for (int k = 0; k < 16; k++) {
            float2 uu = Us[r * 16 + k];
            ar += uu.x * re0[k] - uu.y * im0[k];
            ai += uu.x * im0[k] + uu.y * re0[k];
        }
        float p = ar * ar + ai * ai;
        o0 += (r & 8) ? -p : p;
        o1 += (r & 4) ? -p : p;
        o2 += (r & 2) ? -p : p;
        o3 += (r & 1) ? -p : p;
    }
    float4 ov = {o0, o1, o2, o3};
    ((float4*)out)[s] = ov;
}

// ---------------------------------------------------------------------------
extern "C" void kernel_launch(void* const* d_in, const int* in_sizes, int n_in,
                              void* d_out, int out_size, void* d_ws, size_t ws_size,
                              hipStream_t stream)
{
    const float* x   = (const float*)d_in[0];
    const float* c1w = (const float*)d_in[1];
    const float* c1b = (const float*)d_in[2];
    const float* c2w = (const float*)d_in[3];
    const float* c2b = (const float*)d_in[4];
    const float* f1w = (const float*)d_in[5];
    const float* f1b = (const float*)d_in[6];
    const float* f2w = (const float*)d_in[7];
    const float* f2b = (const float*)d_in[8];
    const float* bng = (const float*)d_in[9];
    const float* bnb = (const float*)d_in[10];
    const float* rl  = (const float*)d_in[11];
    float* out = (float*)d_out;

    int B = in_sizes[0] / 784;

    float* wsf   = (float*)d_ws;
    float* flat  = wsf;                          // B*784
    float* feat  = flat + (size_t)B * 784;       // B*4
    float* wT    = feat + (size_t)B * 4;         // 784*64
    float* U     = wT + 784 * 64;                // 512 (float2[256])
    float* stats = U + 512;                      // 8

    prep_kernel<<<197, 256, 0, stream>>>(rl, f1w, U, wT, stats);
    conv_kernel<<<B / 2, 256, 0, stream>>>(x, c1w, c1b, c2w, c2b, flat);
    fc_kernel<<<B / 16, 256, 0, stream>>>(flat, wT, f1b, f2w, f2b, feat, stats);
    quantum_kernel<<<B / 128, 128, 0, stream>>>(feat, U, stats, bng, bnb, out, B);
}

// Round 7
// 233.375 us; speedup vs baseline: 1.1968x; 1.0300x over previous
//
#include <hip/hip_runtime.h>
#include <hip/hip_bf16.h>

// ---------------------------------------------------------------------------
// QuantumImageEncoder R7: revert conv2 to R2's proven fp32 VALU path; FUSE
// fc1+fc2+BN-stat accumulation into the conv kernel (flat never leaves LDS).
// Stats sharded 64-way to kill atomic contention; quantum gathers shards.
// 3 launches: prep -> conv(+fc) -> quantum.
// ---------------------------------------------------------------------------

#define B_EPS 1e-5f

// ---------------- prep: build U (block 0, + zero 512-float stats) +
// ----------------       transpose fc1_w (blocks 1..196) ---------------------
__global__ void prep_kernel(const float* __restrict__ rl,
                            const float* __restrict__ f1w,
                            float* __restrict__ Uout,
                            float* __restrict__ wT,
                            float* __restrict__ stats)
{
    if (blockIdx.x == 0) {
        __shared__ float2 U[16][16];
        int t = threadIdx.x;                 // 256 threads
        int r = t >> 4, cc = t & 15;
        U[r][cc] = (r == cc) ? make_float2(1.f, 0.f) : make_float2(0.f, 0.f);
        stats[t] = 0.f;                      // 512-float sharded stats
        stats[t + 256] = 0.f;
        __syncthreads();
        for (int op = 0; op < 30; op++) {
            int kind = op & 3;               // 0=rx,1=ry,2=rz,3=cnot ; wire = op%4
            float2 cur = U[r][cc];
            float2 nv;
            if (kind == 3) {
                float2 part = U[r ^ 8][cc];  // control wire3 (bit 1), target wire0 (bit 8)
                nv = (r & 1) ? part : cur;
            } else {
                int m = 8 >> kind;           // wire w=kind -> bit (3-w)
                float theta = rl[op - (op >> 2)];
                float ch = cosf(0.5f * theta), sh = sinf(0.5f * theta);
                float2 part = U[r ^ m][cc];
                int br = (r & m) ? 1 : 0;
                float2 gc, gp;
                if (kind == 0)      { gc = make_float2(ch, 0.f);           gp = make_float2(0.f, -sh); }
                else if (kind == 1) { gc = make_float2(ch, 0.f);           gp = make_float2(br ? sh : -sh, 0.f); }
                else                { gc = make_float2(ch, br ? sh : -sh); gp = make_float2(0.f, 0.f); }
                nv.x = gc.x*cur.x - gc.y*cur.y + gp.x*part.x - gp.y*part.y;
                nv.y = gc.x*cur.y + gc.y*cur.x + gp.x*part.y + gp.y*part.x;
            }
            __syncthreads();
            U[r][cc] = nv;
            __syncthreads();
        }
        ((float2*)Uout)[t] = U[r][cc];
    } else {
        int id = (blockIdx.x - 1) * 256 + threadIdx.x;
        if (id < 784 * 64) {
            int k = id >> 6, o = id & 63;
            wT[id] = f1w[o * 784 + k];
        }
    }
}

// ---------------- conv backbone + fused fc: 2 samples / block, 4 waves ------
// P1-P3 are R2's proven conv path (conflict-free broadcast LDS layout).
// P5: fc1 (lane=neuron, wave=(sample,k-half), wT coalesced from L2)
// P6: +bias/relu; P7: fc2 + feat write + sharded BN-stat atomics.
__global__ __launch_bounds__(256) void conv_kernel(
    const float* __restrict__ x,  const float* __restrict__ c1w,
    const float* __restrict__ c1b, const float* __restrict__ c2w,
    const float* __restrict__ c2b, const float* __restrict__ wT,
    const float* __restrict__ f1b, const float* __restrict__ f2w,
    const float* __restrict__ f2bias, float* __restrict__ feat,
    float* __restrict__ stats)
{
    __shared__ union alignas(16) {
        float xin[2][30 * 32];     // padded 28x28, row stride 32, halo ring
        float flat[2][800];        // reused after conv1 (conv2 pooled output)
    } u;
    __shared__ alignas(16) float p1[2][8 * 292];   // [ch][row 16][col 18]+pad, stride 292
    __shared__ float w1s[8][9], b1s[8], w2s[16][73], b2s[16];
    __shared__ float part[4][64];                  // fc1 partials per wave
    __shared__ float hs[2][64];                    // fc1 activations

    int t = threadIdx.x;
    int w = t >> 6, lane = t & 63;

    // ---- P1: zero xin + p1 (halo correctness), load weights
    {
        float4 z = make_float4(0.f, 0.f, 0.f, 0.f);
        float4* xz = (float4*)u.xin;
        for (int i = t; i < 2 * 30 * 32 / 4; i += 256) xz[i] = z;
        float4* pz = (float4*)p1;
        for (int i = t; i < 2 * 8 * 292 / 4; i += 256) pz[i] = z;
    }
    if (t < 72) ((float*)w1s)[t] = c1w[t];
    if (t < 8)  b1s[t] = c1b[t];
    for (int i = t; i < 16 * 72; i += 256) w2s[i / 72][i % 72] = c2w[i];
    if (t < 16) b2s[t] = c2b[t];
    __syncthreads();

    // ---- stage input (2 samples), shifted +1 for the zero halo
    {
        const float4* xg = (const float4*)(x + (size_t)blockIdx.x * 2 * 784);
        for (int i = t; i < 392; i += 256) {
            float4 v = xg[i];
            int s = i / 196, q = (i - s * 196) * 4;
            float vv[4] = {v.x, v.y, v.z, v.w};
            #pragma unroll
            for (int j = 0; j < 4; j++) {
                int p = q + j, rr = p / 28, cc = p - rr * 28;
                u.xin[s][(rr + 1) * 32 + cc + 1] = vv[j];
            }
        }
    }
    __syncthreads();

    // ---- P2: conv1 + relu + pool -> p1   (lane = (ch, colgroup))
    {
        int s = w >> 1, h = w & 1;
        int c = lane >> 3, g = lane & 7;
        if (g < 7) {
            float wk[9];
            #pragma unroll
            for (int q = 0; q < 9; q++) wk[q] = w1s[c][q];
            float bias = b1s[c];
            const float* xb = &u.xin[s][4 * g];
            float* pout = &p1[s][c * 292];
            for (int ii = 0; ii < 7; ii++) {
                int i = h * 7 + ii;                     // pooled row 0..13
                const float* r = xb + 2 * i * 32;
                float rv[4][6];
                #pragma unroll
                for (int dr = 0; dr < 4; dr++) {
                    float2 a = *(const float2*)(r + dr * 32);
                    float2 b = *(const float2*)(r + dr * 32 + 2);
                    float2 c2v = *(const float2*)(r + dr * 32 + 4);
                    rv[dr][0] = a.x;  rv[dr][1] = a.y;
                    rv[dr][2] = b.x;  rv[dr][3] = b.y;
                    rv[dr][4] = c2v.x; rv[dr][5] = c2v.y;
                }
                float o[2][4];
                #pragma unroll
                for (int dr = 0; dr < 2; dr++)
                    #pragma unroll
                    for (int j = 0; j < 4; j++) {
                        float acc = bias;
                        #pragma unroll
                        for (int ky = 0; ky < 3; ky++)
                            #pragma unroll
                            for (int kx = 0; kx < 3; kx++)
                                acc = fmaf(wk[ky * 3 + kx], rv[dr + ky][j + kx], acc);
                        o[dr][j] = acc;
                    }
                #pragma unroll
                for (int jj = 0; jj < 2; jj++) {
                    float m = fmaxf(fmaxf(o[0][2 * jj], o[0][2 * jj + 1]),
                                    fmaxf(o[1][2 * jj], o[1][2 * jj + 1]));
                    pout[(i + 1) * 18 + 1 + 2 * g + jj] = fmaxf(m, 0.f);
                }
            }
        }
    }
    __syncthreads();

    // ---- P3: conv2 + relu + pool -> u.flat (xin dead now)
    {
        int s = w >> 1, h = w & 1;
        int c2 = lane >> 2, g2 = lane & 3;
        int i0 = h * 4;                                 // h=0: i 0..3, h=1: i 4..6
        float bias = b2s[c2];
        float acc[4][2][4];
        #pragma unroll
        for (int ii = 0; ii < 4; ii++)
            #pragma unroll
            for (int dr = 0; dr < 2; dr++)
                #pragma unroll
                for (int j = 0; j < 4; j++) acc[ii][dr][j] = bias;

        const float* pbase = &p1[s][4 * g2] + i0 * 2 * 18;
        for (int ci = 0; ci < 8; ci++) {
            float wk[9];
            #pragma unroll
            for (int q = 0; q < 9; q++) wk[q] = w2s[c2][ci * 9 + q];
            const float* pc_ = pbase + ci * 292;
            #pragma unroll
            for (int ii = 0; ii < 4; ii++) {
                if (ii < 3 || h == 0) {
                    float rv[4][6];
                    #pragma unroll
                    for (int dr = 0; dr < 4; dr++) {
                        const float* rp = pc_ + (ii * 2 + dr) * 18;
                        float2 a = *(const float2*)rp;
                        float2 b = *(const float2*)(rp + 2);
                        float2 cc = *(const float2*)(rp + 4);
                        rv[dr][0] = a.x;  rv[dr][1] = a.y;
                        rv[dr][2] = b.x;  rv[dr][3] = b.y;
                        rv[dr][4] = cc.x; rv[dr][5] = cc.y;
                    }
                    #pragma unroll
                    for (int dr = 0; dr < 2; dr++)
                        #pragma unroll
                        for (int j = 0; j < 4; j++) {
                            float a2 = acc[ii][dr][j];
                            #pragma unroll
                            for (int ky = 0; ky < 3; ky++)
                                #pragma unroll
                                for (int kx = 0; kx < 3; kx++)
                                    a2 = fmaf(wk[ky * 3 + kx], rv[dr + ky][j + kx], a2);
                            acc[ii][dr][j] = a2;
                        }
                }
            }
        }
        #pragma unroll
        for (int ii = 0; ii < 4; ii++) {
            if (ii < 3 || h == 0) {
                int i = i0 + ii;
                #pragma unroll
                for (int jj = 0; jj < 2; jj++) {
                    int pc = 2 * g2 + jj;
                    if (pc < 7) {
                        float m = fmaxf(fmaxf(acc[ii][0][2 * jj], acc[ii][0][2 * jj + 1]),
                                        fmaxf(acc[ii][1][2 * jj], acc[ii][1][2 * jj + 1]));
                        u.flat[s][c2 * 49 + i * 7 + pc] = fmaxf(m, 0.f);
                    }
                }
            }
        }
    }
    __syncthreads();

    // ---- P5: fc1 partials. wave w -> (sample s, k-half h2); lane = neuron.
    {
        int s = w >> 1, h2 = w & 1;
        const float* fl = u.flat[s];
        const float* wp = wT + lane;
        int k0 = h2 * 392;
        float a0 = 0.f, a1 = 0.f, a2 = 0.f, a3 = 0.f;
        for (int k = k0; k < k0 + 392; k += 4) {
            a0 = fmaf(fl[k    ], wp[(k    ) * 64], a0);
            a1 = fmaf(fl[k + 1], wp[(k + 1) * 64], a1);
            a2 = fmaf(fl[k + 2], wp[(k + 2) * 64], a2);
            a3 = fmaf(fl[k + 3], wp[(k + 3) * 64], a3);
        }
        part[w][lane] = (a0 + a1) + (a2 + a3);
    }
    __syncthreads();

    // ---- P6: combine halves + bias + relu
    if (t < 128) {
        int s = t >> 6, o = t & 63;
        float h = part[2 * s][o] + part[2 * s + 1][o] + f1b[o];
        hs[s][o] = fmaxf(h, 0.f);
    }
    __syncthreads();

    // ---- P7: fc2 + feat + sharded BN stats
    if (t < 8) {
        int s = t >> 2, j = t & 3;
        float a = f2bias[j];
        #pragma unroll
        for (int o = 0; o < 64; o++) a = fmaf(hs[s][o], f2w[j * 64 + o], a);
        feat[((size_t)blockIdx.x * 2 + s) * 4 + j] = a;
        int g = blockIdx.x & 63;
        atomicAdd(&stats[g * 8 + j], a);
        atomicAdd(&stats[g * 8 + 4 + j], a * a);
    }
}

// ---------------- BN + encoder + U matvec + PauliZ measure ------------------
__global__ __launch_bounds__(128) void quantum_kernel(
    const float* __restrict__ feat, const float* __restrict__ Ug,
    const float* __restrict__ stats, const float* __restrict__ bn_g,
    const float* __restrict__ bn_b, float* __restrict__ out, int B)
{
    __shared__ float2 Us[256];
    __shared__ float sm[8];
    int t = threadIdx.x;
    for (int i = t; i < 256; i += 128) Us[i] = ((const float2*)Ug)[i];
    if (t < 8) {                         // gather 64 stat shards
        float a = 0.f;
        for (int g = 0; g < 64; g++) a += stats[g * 8 + t];
        sm[t] = a;
    }
    __syncthreads();
    int s = blockIdx.x * 128 + t;
    float4 fv = ((const float4*)feat)[s];
    float f[4] = {fv.x, fv.y, fv.z, fv.w};
    float cn[4], sn[4];
    float invB = 1.0f / (float)B;
    #pragma unroll
    for (int w = 0; w < 4; w++) {
        float mean = sm[w] * invB;
        float var  = sm[4 + w] * invB - mean * mean;
        float fh = (f[w] - mean) / sqrtf(var + B_EPS) * bn_g[w] + bn_b[w];
        cn[w] = cosf(0.5f * fh);
        sn[w] = sinf(0.5f * fh);
    }
    // encoded product state: s0_k = prod(c/s) * (-i)^popcount(k)
    float re0[16], im0[16];
    #pragma unroll
    for (int k = 0; k < 16; k++) {
        float mag = ((k & 8) ? sn[0] : cn[0]) * ((k & 4) ? sn[1] : cn[1]) *
                    ((k & 2) ? sn[2] : cn[2]) * ((k & 1) ? sn[3] : cn[3]);
        int m = __popc(k) & 3;
        re0[k] = (m == 0) ? mag : (m == 2) ? -mag : 0.f;
        im0[k] = (m == 1) ? -mag : (m == 3) ? mag : 0.f;
    }
    float o0 = 0.f, o1 = 0.f, o2 = 0.f, o3 = 0.f;
    #pragma unroll
    for (int r = 0; r < 16; r++) {
        float ar = 0.f, ai = 0.f;
        #pragma unroll
        for (int k = 0; k < 16; k++) {
            float2 uu = Us[r * 16 + k];
            ar += uu.x * re0[k] - uu.y * im0[k];
            ai += uu.x * im0[k] + uu.y * re0[k];
        }
        float p = ar * ar + ai * ai;
        o0 += (r & 8) ? -p : p;
        o1 += (r & 4) ? -p : p;
        o2 += (r & 2) ? -p : p;
        o3 += (r & 1) ? -p : p;
    }
    float4 ov = {o0, o1, o2, o3};
    ((float4*)out)[s] = ov;
}

// ---------------------------------------------------------------------------
extern "C" void kernel_launch(void* const* d_in, const int* in_sizes, int n_in,
                              void* d_out, int out_size, void* d_ws, size_t ws_size,
                              hipStream_t stream)
{
    const float* x   = (const float*)d_in[0];
    const float* c1w = (const float*)d_in[1];
    const float* c1b = (const float*)d_in[2];
    const float* c2w = (const float*)d_in[3];
    const float* c2b = (const float*)d_in[4];
    const float* f1w = (const float*)d_in[5];
    const float* f1b = (const float*)d_in[6];
    const float* f2w = (const float*)d_in[7];
    const float* f2b = (const float*)d_in[8];
    const float* bng = (const float*)d_in[9];
    const float* bnb = (const float*)d_in[10];
    const float* rl  = (const float*)d_in[11];
    float* out = (float*)d_out;

    int B = in_sizes[0] / 784;

    float* wsf   = (float*)d_ws;
    float* feat  = wsf;                          // B*4
    float* wT    = feat + (size_t)B * 4;         // 784*64
    float* U     = wT + 784 * 64;                // 512 (float2[256])
    float* stats = U + 512;                      // 512 (64 shards x 8)

    prep_kernel<<<197, 256, 0, stream>>>(rl, f1w, U, wT, stats);
    conv_kernel<<<B / 2, 256, 0, stream>>>(x, c1w, c1b, c2w, c2b, wT,
                                           f1b, f2w, f2b, feat, stats);
    quantum_kernel<<<B / 128, 128, 0, stream>>>(feat, U, stats, bng, bnb, out, B);
}